// Round 7
// baseline (211.445 us; speedup 1.0000x reference)
//
#include <hip/hip_runtime.h>
#include <stdint.h>

#define EPS 1e-8f

constexpr int HW = 16384;   // pixels per image (M and N dims)
constexpr int BM = 128;     // block M tile
constexpr int NG = 2048;    // n-group width per block (32 q-substeps of 64)

typedef __attribute__((ext_vector_type(4))) float floatx4;
typedef __attribute__((ext_vector_type(4))) int   intx4;
typedef __attribute__((ext_vector_type(8))) int   intx8;    // 32B = one f8f6f4 K=128 operand
typedef unsigned char u8;
typedef unsigned int u32;
typedef unsigned long long u64;

// Address-space-qualified pointers for global_load_lds (hipcc does NOT
// implicitly convert generic pointers to AS(1)/AS(3) builtin params).
typedef const __attribute__((address_space(1))) u32 gas_u32;
typedef __attribute__((address_space(3))) u32 las_u32;
__device__ inline void stage16(const void* g, void* l) {
    __builtin_amdgcn_global_load_lds((gas_u32*)g, (las_u32*)l, 16, 0, 0);
}

// HW packed fp8 e4m3 convert: 4 floats -> 4 bytes (2x v_cvt_pk_fp8_f32)
__device__ inline u32 pk4(float x0, float x1, float x2, float x3) {
    int t = __builtin_amdgcn_cvt_pk_fp8_f32(x0, x1, 0, false);
    t = __builtin_amdgcn_cvt_pk_fp8_f32(x2, x3, t, true);
    return (u32)t;
}

__device__ inline float getc(const float4& f, int j) {
    return (j == 0) ? f.x : (j == 1) ? f.y : (j == 2) ? f.z : f.w;
}

// ---------------------------------------------------------------------------
// Fragment layout (split-half, ds_read-conflict-free): pixel p, channel c:
//   g = p>>4 (16-px slab), r = p&15, kb = c>>7, q = (c>>5)&3, h = (c>>4)&1,
//   e8 = c&15;  byte = g*4096 + kb*2048 + h*1024 + (q*16+r)*16 + e8
// Lane (q*16+r) of an MFMA operand assembles its 32 contiguous k-bytes from
// two 16B halves at +0/+1024 (lane-stride-16 b128 = conflict-free banking,
// R4 measured SQ_LDS_BANK_CONFLICT = 0).
// A 64-col slice (4 slabs) is 16KB CONTIGUOUS -> linear global_load_lds.
//
// PREP (R6 post-mortem: ~50us vs 6.4us HBM floor; the 64-iter serial LDS
// reduce by a half-wave + 2 blocks/CU was the tail): now 1024 blocks x 256
// thr (16 px/block, 4+ blocks/CU) with a two-stage parallel reduce
// (128 thr x 8 adds -> 16 thr x 8 adds). Same loads/stores/layout.
__global__ __launch_bounds__(256) void prep_kernel(const float* __restrict__ a,
                                                   const float* __restrict__ b,
                                                   float* __restrict__ sumsq_a,
                                                   float* __restrict__ sumsq_b,
                                                   u8* __restrict__ aF, u8* __restrict__ bF,
                                                   u64* __restrict__ packed,
                                                   float* __restrict__ out) {
    __shared__ float red[64][17];
    __shared__ float p2[8][17];
    __shared__ float invb_sh[16];
    const int tid = threadIdx.x;
    const int pg = tid & 3, tc = tid >> 2;          // tc 0..63: channels tc*4..+3
    const int p0 = blockIdx.x * 16, pb = pg * 4;    // pixels pb..+3
    const int c0 = tc * 4;
    const u32 fb = (u32)((c0 >> 7) * 2048 + ((c0 >> 4) & 1) * 1024 + (c0 & 15));
    const u32 qr16 = (u32)(((c0 >> 5) & 3) * 16);   // q*16 (row offset added per pixel)
    const int px = tid & 15, oct = tid >> 4;        // stage-2 reduce roles

    if (tid < 16) packed[(size_t)blockIdx.x * 16 + tid] = 0ull;
    if (blockIdx.x == 0 && tid == 0) *out = 0.f;

    // hoisted loads (8 independent float4 in flight)
    float4 bv[4], av[4];
    #pragma unroll
    for (int i = 0; i < 4; ++i)
        bv[i] = *(const float4*)&b[(size_t)(c0 + i) * HW + p0 + pb];
    #pragma unroll
    for (int i = 0; i < 4; ++i)
        av[i] = *(const float4*)&a[(size_t)(c0 + i) * HW + p0 + pb];

    float s0 = 0.f, s1 = 0.f, s2 = 0.f, s3 = 0.f;
    #pragma unroll
    for (int i = 0; i < 4; ++i) {
        s0 += bv[i].x * bv[i].x; s1 += bv[i].y * bv[i].y;
        s2 += bv[i].z * bv[i].z; s3 += bv[i].w * bv[i].w;
    }
    red[tc][pb] = s0; red[tc][pb + 1] = s1; red[tc][pb + 2] = s2; red[tc][pb + 3] = s3;
    __syncthreads();
    if (tid < 128) {                // 16 px x 8 octets, 8 adds each
        float s = 0.f;
        #pragma unroll
        for (int j = 0; j < 8; ++j) s += red[oct * 8 + j][px];
        p2[oct][px] = s;
    }
    __syncthreads();
    if (tid < 16) {
        float B = 0.f;
        #pragma unroll
        for (int j = 0; j < 8; ++j) B += p2[j][tid];
        sumsq_b[p0 + tid] = B;
        invb_sh[tid] = 1.0f / (sqrtf(B + EPS) + EPS);
    }
    __syncthreads();

    // b fragment stores (normalized), one u32 per pixel
    #pragma unroll
    for (int j = 0; j < 4; ++j) {
        const int p = p0 + pb + j;
        const float inv = invb_sh[pb + j];
        u32 wv = pk4(getc(bv[0], j) * inv, getc(bv[1], j) * inv,
                     getc(bv[2], j) * inv, getc(bv[3], j) * inv);
        *(u32*)(bF + ((size_t)(p >> 4) << 12) + fb + (qr16 + (u32)(p & 15)) * 16) = wv;
    }

    // a: sumsq partials + raw fragment stores
    s0 = s1 = s2 = s3 = 0.f;
    #pragma unroll
    for (int i = 0; i < 4; ++i) {
        s0 += av[i].x * av[i].x; s1 += av[i].y * av[i].y;
        s2 += av[i].z * av[i].z; s3 += av[i].w * av[i].w;
    }
    __syncthreads();                // red reuse safe
    red[tc][pb] = s0; red[tc][pb + 1] = s1; red[tc][pb + 2] = s2; red[tc][pb + 3] = s3;
    #pragma unroll
    for (int j = 0; j < 4; ++j) {
        const int p = p0 + pb + j;
        u32 wv = pk4(getc(av[0], j), getc(av[1], j), getc(av[2], j), getc(av[3], j));
        *(u32*)(aF + ((size_t)(p >> 4) << 12) + fb + (qr16 + (u32)(p & 15)) * 16) = wv;
    }
    __syncthreads();
    if (tid < 128) {
        float s = 0.f;
        #pragma unroll
        for (int j = 0; j < 8; ++j) s += red[oct * 8 + j][px];
        p2[oct][px] = s;
    }
    __syncthreads();
    if (tid < 16) {
        float A = 0.f;
        #pragma unroll
        for (int j = 0; j < 8; ++j) A += p2[j][tid];
        sumsq_a[p0 + tid] = A;
    }
}

// ---------------------------------------------------------------------------
// G: fused GEMM + argmax, MX-scaled fp8 (unit scales). R4 structure (best
// verified: 70us, 256 thr, 4 waves, wave tile 64x32, 3 blocks/CU) with ONE
// change: the per-qt __syncthreads (vmcnt(0) drain of the just-issued
// next-tile stage = R4's ~40us stall) is replaced by a depth-3 LDS ring +
// raw s_barrier + counted s_waitcnt vmcnt(4) (T3/T4: never drain to 0 in
// the loop). At iter t's wait: outstanding = {t:4, t+1:4} -> vmcnt(4)
// retires exactly tile t (FIFO). Slot (t+2)%3 is re-staged only after the
// barrier proving all waves finished reading tile t-1 (same slot). Loads
// get ~2 iterations of latency cover instead of a synchronous drain.
#define MFMA1(A_, B_, C_) __builtin_amdgcn_mfma_scale_f32_16x16x128_f8f6f4( \
        (A_), (B_), (C_), 0, 0, 0, SCL, 0, SCL)

#define LDB(off_) __builtin_shufflevector(                                  \
        *(const intx4*)(Lb + (off_)), *(const intx4*)(Lb + (off_) + 1024),  \
        0, 1, 2, 3, 4, 5, 6, 7)

#define STAGE(slot_, qt_) do {                                              \
    const u8* gs_ = gQ + (u32)(qt_) * 16384u + so;                          \
    u8* ls_ = sB0 + (u32)(slot_) * 16384u + wso;                            \
    stage16(gs_,        ls_);                                               \
    stage16(gs_ + 1024, ls_ + 1024);                                        \
    stage16(gs_ + 2048, ls_ + 2048);                                        \
    stage16(gs_ + 3072, ls_ + 3072);                                        \
} while (0)

#define COMPUTE_QT(sc_, qc_) do {                                           \
    const u8* Lb = sB0 + (u32)(sc_) * 16384u                                \
                 + (u32)(wn * 2) * 4096u + (u32)lane * 16u;                 \
    floatx4 acc[4][2];                                                      \
    intx8 Bk0n0 = LDB(0);                                                   \
    intx8 Bk0n1 = LDB(4096);                                                \
    __builtin_amdgcn_s_setprio(1);                                          \
    _Pragma("unroll")                                                       \
    for (int mi = 0; mi < 4; ++mi) {                                        \
        acc[mi][0] = MFMA1(Afr[mi][0], Bk0n0, C64);                         \
        acc[mi][1] = MFMA1(Afr[mi][0], Bk0n1, C64);                         \
    }                                                                       \
    __builtin_amdgcn_s_setprio(0);                                          \
    intx8 Bk1n0 = LDB(2048);                                                \
    intx8 Bk1n1 = LDB(4096 + 2048);                                         \
    __builtin_amdgcn_s_setprio(1);                                          \
    _Pragma("unroll")                                                       \
    for (int mi = 0; mi < 4; ++mi) {                                        \
        acc[mi][0] = MFMA1(Afr[mi][1], Bk1n0, acc[mi][0]);                  \
        acc[mi][1] = MFMA1(Afr[mi][1], Bk1n1, acc[mi][1]);                  \
    }                                                                       \
    __builtin_amdgcn_s_setprio(0);                                          \
    _Pragma("unroll")                                                       \
    for (int mi = 0; mi < 4; ++mi) {                                        \
        _Pragma("unroll")                                                   \
        for (int ni = 0; ni < 2; ++ni) {                                    \
            const u32 qn_ = (qc_) + (u32)(ni * 16);                         \
            _Pragma("unroll")                                               \
            for (int r = 0; r < 4; ++r) {                                   \
                float v_ = acc[mi][ni][r];                                  \
                bool gt_ = v_ > bestv[mi][r];                               \
                bestv[mi][r] = gt_ ? v_ : bestv[mi][r];                     \
                bestq[mi][r] = gt_ ? qn_ : bestq[mi][r];                    \
            }                                                               \
        }                                                                   \
    }                                                                       \
} while (0)

__global__ __launch_bounds__(256, 3) void gemm_argmax(const u8* __restrict__ aF,
                                                      const u8* __restrict__ bF,
                                                      u64* __restrict__ packed) {
    __shared__ u8 sB[3][16384];     // depth-3 ring, 48KB -> 3 blocks/CU
    u8* sB0 = &sB[0][0];
    const int tid = threadIdx.x;
    const int w = tid >> 6, lane = tid & 63;
    const int q4 = lane >> 4, r15 = lane & 15;
    const int wm = w >> 1, wn = w & 1;     // 2m x 2n waves, wave tile 64x32

    const u32 bid = blockIdx.x;
    const u32 ng = bid & 7;          // n-group -> XCD (L2-resident B panel)
    const u32 mt = bid >> 3;         // 0..127 M tile
    const int p0 = (int)mt * BM;

    // A fragments resident: slab g = mt*8 + wm*4 + mi; two 16B halves at
    // g*4096 + kb*2048 + {0,1024} + lane*16
    const u8* gA = aF + (((size_t)(mt * 8 + wm * 4)) << 12) + (u32)lane * 16;
    intx8 Afr[4][2];
    #pragma unroll
    for (int mi = 0; mi < 4; ++mi)
        #pragma unroll
        for (int kb = 0; kb < 2; ++kb)
            Afr[mi][kb] = __builtin_shufflevector(
                *(const intx4*)(gA + (u32)(mi * 4096 + kb * 2048)),
                *(const intx4*)(gA + (u32)(mi * 4096 + kb * 2048 + 1024)),
                0, 1, 2, 3, 4, 5, 6, 7);

    // B panel for this ng: qt slice = gQ + qt*16384, 16KB contiguous
    const u8* gQ = bF + ((size_t)ng << 19);
    const u32 so  = (u32)w * 4096u + (u32)lane * 16u;   // stage src offset
    const u32 wso = (u32)w * 4096u;                      // LDS dest (wave-uniform)

    float bestv[4][4];
    u32   bestq[4][4];
    #pragma unroll
    for (int mi = 0; mi < 4; ++mi)
        #pragma unroll
        for (int r = 0; r < 4; ++r) { bestv[mi][r] = -3.4e38f; bestq[mi][r] = 0; }

    u32 qcur = ng * 2048 + wn * 32 + (u32)r15;   // running col id (ni0); ni1 = +16
    const floatx4 C64 = {64.f, 64.f, 64.f, 64.f};
    const int SCL = 0x7F7F7F7F;      // E8M0 127 = 2^0 -> unit scale

    // prologue: tiles 0,1 in flight (8 loads/wave)
    STAGE(0, 0);
    STAGE(1, 1);

    int sc = 0;                      // slot of tile t
    for (int t = 0; t < 31; ++t) {
        asm volatile("s_waitcnt vmcnt(4)" ::: "memory");   // tile t landed; t+1 in flight
        __builtin_amdgcn_sched_barrier(0);
        __builtin_amdgcn_s_barrier();                      // all waves: t ready, t-1 reads done
        if (t < 30) {
            const int s2 = sc == 0 ? 2 : sc - 1;           // (t+2)%3
            STAGE(s2, t + 2);
        }
        COMPUTE_QT(sc, qcur);
        qcur += 64u;
        sc = sc == 2 ? 0 : sc + 1;
    }
    asm volatile("s_waitcnt vmcnt(0)" ::: "memory");
    __builtin_amdgcn_sched_barrier(0);
    __builtin_amdgcn_s_barrier();
    COMPUTE_QT(sc, qcur);            // tile 31 (slot 1)

    // final: pack (acc = s+64 > 0 -> float bits monotone as uint),
    // shuffle-reduce over r15 (stays in q4 group), 1 atomic/row/wave
    #pragma unroll
    for (int mi = 0; mi < 4; ++mi)
        #pragma unroll
        for (int r = 0; r < 4; ++r) {
            u64 pk = ((u64)__float_as_uint(bestv[mi][r]) << 32)
                   | (u64)(0xFFFFFFFFu - bestq[mi][r]);
            #pragma unroll
            for (int d = 1; d < 16; d <<= 1) {
                u64 o = __shfl_xor((unsigned long long)pk, d);
                pk = o > pk ? o : pk;
            }
            if (r15 == 0)
                atomicMax(&packed[p0 + wm * 64 + mi * 16 + q4 * 4 + r], pk);
        }
}

// ---------------------------------------------------------------------------
// L: loss from the argmax's own similarity value (no gather).
// Decode: hi = bits(s+64) -> s = asfloat(hi) - 64; lo = ~q.
__global__ void loss_kernel(const u64* __restrict__ packed,
                            const float* __restrict__ sumsq_a, const float* __restrict__ sumsq_b,
                            float* __restrict__ out) {
    int p = blockIdx.x * 256 + threadIdx.x;
    u64 pk = packed[p];
    float s = __uint_as_float((u32)(pk >> 32)) - 64.0f;
    u32 q = 0xFFFFFFFFu - (u32)(pk & 0xFFFFFFFFull);
    float A = sumsq_a[p], B = sumsq_b[q];
    float dot = s * (sqrtf(B + EPS) + EPS);
    float cossim = dot / ((sqrtf(A) + EPS) * (sqrtf(B) + EPS));
    float v = (1.0f - cossim) * (1.0f / (float)HW);
    #pragma unroll
    for (int d = 1; d < 64; d <<= 1) v += __shfl_xor(v, d);
    if ((threadIdx.x & 63) == 0) atomicAdd(out, v);
}

// ---------------------------------------------------------------------------
extern "C" void kernel_launch(void* const* d_in, const int* in_sizes, int n_in,
                              void* d_out, int out_size, void* d_ws, size_t ws_size,
                              hipStream_t stream) {
    const float* a = (const float*)d_in[0];
    const float* b = (const float*)d_in[1];
    float* out = (float*)d_out;
    char* ws = (char*)d_ws;

    u8*    aF      = (u8*)ws;                                    // 4 MB
    u8*    bF      = (u8*)(ws + (size_t)4 * 1024 * 1024);        // 4 MB
    float* sumsq_a = (float*)(ws + (size_t)8 * 1024 * 1024);     // 64 KB
    float* sumsq_b = sumsq_a + HW;
    u64*   packed  = (u64*)(sumsq_b + HW);                       // 128 KB

    prep_kernel<<<dim3(HW / 16), 256, 0, stream>>>(a, b, sumsq_a, sumsq_b, aF, bF, packed, out);
    gemm_argmax<<<dim3((HW / BM) * (HW / NG)), 256, 0, stream>>>(aF, bF, packed);
    loss_kernel<<<dim3(HW / 256), 256, 0, stream>>>(packed, sumsq_a, sumsq_b, out);
}

// Round 8
// 154.727 us; speedup vs baseline: 1.3666x; 1.3666x over previous
//
#include <hip/hip_runtime.h>
#include <stdint.h>

#define EPS 1e-8f

constexpr int HW = 16384;   // pixels per image (M and N dims)
constexpr int BM = 128;     // block M tile
constexpr int NG = 2048;    // n-group width per block (32 q-substeps of 64)

typedef __attribute__((ext_vector_type(4))) float floatx4;
typedef __attribute__((ext_vector_type(4))) int   intx4;
typedef __attribute__((ext_vector_type(8))) int   intx8;    // 32B = one f8f6f4 K=128 operand
typedef unsigned char u8;
typedef unsigned int u32;
typedef unsigned long long u64;

// Address-space-qualified pointers for global_load_lds (hipcc does NOT
// implicitly convert generic pointers to AS(1)/AS(3) builtin params).
typedef const __attribute__((address_space(1))) u32 gas_u32;
typedef __attribute__((address_space(3))) u32 las_u32;
__device__ inline void stage16(const void* g, void* l) {
    __builtin_amdgcn_global_load_lds((gas_u32*)g, (las_u32*)l, 16, 0, 0);
}

// HW packed fp8 e4m3 convert: 4 floats -> 4 bytes (2x v_cvt_pk_fp8_f32)
__device__ inline u32 pk4(float x0, float x1, float x2, float x3) {
    int t = __builtin_amdgcn_cvt_pk_fp8_f32(x0, x1, 0, false);
    t = __builtin_amdgcn_cvt_pk_fp8_f32(x2, x3, t, true);
    return (u32)t;
}

__device__ inline float getc(const float4& f, int j) {
    return (j == 0) ? f.x : (j == 1) ? f.y : (j == 2) ? f.z : f.w;
}

// ---------------------------------------------------------------------------
// PREP1 (R7 post-mortem: prep's 64B-per-channel-per-block reads = DRAM row
// thrash, ~55us across all variants): fully-coalesced sumsq pass.
// Thread = pixel; each wave reads 256B contiguous per channel step.
// 1024 blocks x 256 thr: pg = bid>>4 (256-px group), cg = bid&15 (16-ch group).
// Writes deterministic partials apart/bpart[cg][p]. Also zeroes packed/out.
__global__ __launch_bounds__(256) void prep1_kernel(const float* __restrict__ a,
                                                    const float* __restrict__ b,
                                                    float* __restrict__ apart,
                                                    float* __restrict__ bpart,
                                                    u64* __restrict__ packed,
                                                    float* __restrict__ out) {
    const int tid = threadIdx.x;
    const u32 bid = blockIdx.x;
    const int pg = (int)(bid >> 4), cg = (int)(bid & 15);
    const int p = pg * 256 + tid;
    const int c0 = cg * 16;

    if (bid < 64) packed[(size_t)bid * 256 + tid] = 0ull;
    if (bid == 0 && tid == 0) *out = 0.f;

    float sb = 0.f, sa = 0.f;
    #pragma unroll
    for (int i = 0; i < 16; ++i) {
        float xb = b[(size_t)(c0 + i) * HW + p];
        sb += xb * xb;
    }
    #pragma unroll
    for (int i = 0; i < 16; ++i) {
        float xa = a[(size_t)(c0 + i) * HW + p];
        sa += xa * xa;
    }
    bpart[(size_t)cg * HW + p] = sb;
    apart[(size_t)cg * HW + p] = sa;
}

// ---------------------------------------------------------------------------
// Fragment layout (split-half, ds_read-conflict-free): pixel p, channel c:
//   g = p>>4 (16-px slab), r = p&15, kb = c>>7, q = (c>>5)&3, h = (c>>4)&1,
//   e8 = c&15;  byte = g*4096 + kb*2048 + h*1024 + (q*16+r)*16 + e8
// A 64-col slice (4 slabs) is 16KB CONTIGUOUS -> linear global_load_lds.
//
// PREP2: deterministic partial-sum reduce (16 adds) + the R7-verified
// conversion/fragment stores. The 64B-per-channel loads of a/b are now
// L3-resident (prep1 just streamed all 64MB through the 256MB MALL).
__global__ __launch_bounds__(256) void prep2_kernel(const float* __restrict__ a,
                                                    const float* __restrict__ b,
                                                    const float* __restrict__ apart,
                                                    const float* __restrict__ bpart,
                                                    float* __restrict__ sumsq_a,
                                                    float* __restrict__ sumsq_b,
                                                    u8* __restrict__ aF, u8* __restrict__ bF) {
    __shared__ float invb_sh[16];
    const int tid = threadIdx.x;
    const int pg = tid & 3, tc = tid >> 2;          // tc 0..63: channels tc*4..+3
    const int p0 = blockIdx.x * 16, pb = pg * 4;    // pixels pb..+3
    const int c0 = tc * 4;
    const u32 fb = (u32)((c0 >> 7) * 2048 + ((c0 >> 4) & 1) * 1024 + (c0 & 15));
    const u32 qr16 = (u32)(((c0 >> 5) & 3) * 16);   // q*16 (row offset added per pixel)

    if (tid < 16) {
        const int p = p0 + tid;
        float B = 0.f, A = 0.f;
        #pragma unroll
        for (int j = 0; j < 16; ++j) {
            B += bpart[(size_t)j * HW + p];
            A += apart[(size_t)j * HW + p];
        }
        sumsq_b[p] = B;
        sumsq_a[p] = A;
        invb_sh[tid] = 1.0f / (sqrtf(B + EPS) + EPS);
    }

    // hoisted loads (8 independent float4 in flight, L3-warm)
    float4 bv[4], av[4];
    #pragma unroll
    for (int i = 0; i < 4; ++i)
        bv[i] = *(const float4*)&b[(size_t)(c0 + i) * HW + p0 + pb];
    #pragma unroll
    for (int i = 0; i < 4; ++i)
        av[i] = *(const float4*)&a[(size_t)(c0 + i) * HW + p0 + pb];
    __syncthreads();

    // b fragment stores (normalized), one u32 per pixel
    #pragma unroll
    for (int j = 0; j < 4; ++j) {
        const int p = p0 + pb + j;
        const float inv = invb_sh[pb + j];
        u32 wv = pk4(getc(bv[0], j) * inv, getc(bv[1], j) * inv,
                     getc(bv[2], j) * inv, getc(bv[3], j) * inv);
        *(u32*)(bF + ((size_t)(p >> 4) << 12) + fb + (qr16 + (u32)(p & 15)) * 16) = wv;
    }
    // a raw fragment stores
    #pragma unroll
    for (int j = 0; j < 4; ++j) {
        const int p = p0 + pb + j;
        u32 wv = pk4(getc(av[0], j), getc(av[1], j), getc(av[2], j), getc(av[3], j));
        *(u32*)(aF + ((size_t)(p >> 4) << 12) + fb + (qr16 + (u32)(p & 15)) * 16) = wv;
    }
}

// ---------------------------------------------------------------------------
// G: fused GEMM + argmax, MX-scaled fp8 (unit scales) — VERBATIM R4
// structure (best verified: 70.4us, MfmaUtil 40%, 0 spills, 0 conflicts).
// R5/R6/R7 post-mortems: acc-dbuf and ring+counted-vmcnt rewrites both
// exploded register pressure (WRITE 8->57/65MB scratch). Keep the simple
// 2-buffer __syncthreads schedule; wave tile 64x32, 3 blocks/CU.
__global__ __launch_bounds__(256, 3) void gemm_argmax(const u8* __restrict__ aF,
                                                      const u8* __restrict__ bF,
                                                      u64* __restrict__ packed) {
    __shared__ u8 sB[2][16384];
    const int tid = threadIdx.x;
    const int w = tid >> 6, lane = tid & 63;
    const int q4 = lane >> 4, r15 = lane & 15;
    const int wm = w >> 1, wn = w & 1;

    const u32 bid = blockIdx.x;
    const u32 ng = bid & 7;          // n-group -> XCD (L2-resident B panel)
    const u32 mt = bid >> 3;         // 0..127 M tile
    const int p0 = (int)mt * BM;

    // A fragments resident: slab g = mt*8 + wm*4 + mi; two 16B halves at
    // g*4096 + kb*2048 + {0,1024} + lane*16
    const u8* gA = aF + (((size_t)(mt * 8 + wm * 4)) << 12) + (u32)lane * 16;
    intx8 Afr[4][2];
    #pragma unroll
    for (int mi = 0; mi < 4; ++mi)
        #pragma unroll
        for (int kb = 0; kb < 2; ++kb)
            Afr[mi][kb] = __builtin_shufflevector(
                *(const intx4*)(gA + (u32)(mi * 4096 + kb * 2048)),
                *(const intx4*)(gA + (u32)(mi * 4096 + kb * 2048 + 1024)),
                0, 1, 2, 3, 4, 5, 6, 7);

    // B panel for this ng: qt slice = gQ + qt*16384, 16KB contiguous
    const u8* gQ = bF + ((size_t)ng << 19);
    const u32 so = (u32)w * 4096u + (u32)lane * 16u;    // stage src offset (per-lane)

    // prologue: stage qt=0 into buffer 0
    #pragma unroll
    for (int i = 0; i < 4; ++i)
        stage16(gQ + so + (u32)(i * 1024), &sB[0][w * 4096 + i * 1024]);

    float bestv[4][4];
    u32   bestq[4][4];
    #pragma unroll
    for (int mi = 0; mi < 4; ++mi)
        #pragma unroll
        for (int r = 0; r < 4; ++r) { bestv[mi][r] = -3.4e38f; bestq[mi][r] = 0; }

    u32 q0 = ng * 2048 + wn * 32 + (u32)r15;   // running col id (ni0); ni1 = +16
    const floatx4 C64 = {64.f, 64.f, 64.f, 64.f};
    const int SCL = 0x7F7F7F7F;      // E8M0 127 = 2^0 -> unit scale

    __syncthreads();                 // vmcnt(0) drain + barrier: buf0 ready

    int x = 0;
    for (int qt = 0; qt < 32; ++qt) {
        // stage qt+1 into the other buffer (loads span the whole compute phase)
        if (qt < 31) {
            const u8* gs = gQ + (u32)(qt + 1) * 16384u + so;
            u8* ls = &sB[x ^ 1][w * 4096];
            #pragma unroll
            for (int i = 0; i < 4; ++i)
                stage16(gs + (u32)(i * 1024), ls + i * 1024);
        }

        const u8* Lb = &sB[x][(u32)(wn * 2) * 4096u + (u32)lane * 16u];
        floatx4 acc[4][2];
        intx8 B0, B1;

        // kb = 0 (C = bias 64)
        { intx4 lo = *(const intx4*)(Lb);
          intx4 hi = *(const intx4*)(Lb + 1024);
          B0 = __builtin_shufflevector(lo, hi, 0, 1, 2, 3, 4, 5, 6, 7); }
        { intx4 lo = *(const intx4*)(Lb + 4096);
          intx4 hi = *(const intx4*)(Lb + 4096 + 1024);
          B1 = __builtin_shufflevector(lo, hi, 0, 1, 2, 3, 4, 5, 6, 7); }
        __builtin_amdgcn_s_setprio(1);
        #pragma unroll
        for (int mi = 0; mi < 4; ++mi)
            acc[mi][0] = __builtin_amdgcn_mfma_scale_f32_16x16x128_f8f6f4(
                Afr[mi][0], B0, C64, 0, 0, 0, SCL, 0, SCL);
        #pragma unroll
        for (int mi = 0; mi < 4; ++mi)
            acc[mi][1] = __builtin_amdgcn_mfma_scale_f32_16x16x128_f8f6f4(
                Afr[mi][0], B1, C64, 0, 0, 0, SCL, 0, SCL);
        __builtin_amdgcn_s_setprio(0);

        // kb = 1 (accumulate)
        { intx4 lo = *(const intx4*)(Lb + 2048);
          intx4 hi = *(const intx4*)(Lb + 2048 + 1024);
          B0 = __builtin_shufflevector(lo, hi, 0, 1, 2, 3, 4, 5, 6, 7); }
        { intx4 lo = *(const intx4*)(Lb + 4096 + 2048);
          intx4 hi = *(const intx4*)(Lb + 4096 + 2048 + 1024);
          B1 = __builtin_shufflevector(lo, hi, 0, 1, 2, 3, 4, 5, 6, 7); }
        __builtin_amdgcn_s_setprio(1);
        #pragma unroll
        for (int mi = 0; mi < 4; ++mi)
            acc[mi][0] = __builtin_amdgcn_mfma_scale_f32_16x16x128_f8f6f4(
                Afr[mi][1], B0, acc[mi][0], 0, 0, 0, SCL, 0, SCL);
        #pragma unroll
        for (int mi = 0; mi < 4; ++mi)
            acc[mi][1] = __builtin_amdgcn_mfma_scale_f32_16x16x128_f8f6f4(
                Afr[mi][1], B1, acc[mi][1], 0, 0, 0, SCL, 0, SCL);
        __builtin_amdgcn_s_setprio(0);

        // running argmax (ascending q scan, strict > keeps first = smallest q)
        #pragma unroll
        for (int mi = 0; mi < 4; ++mi)
            #pragma unroll
            for (int r = 0; r < 4; ++r) {
                float v = acc[mi][0][r];
                bool gt = v > bestv[mi][r];
                bestv[mi][r] = gt ? v : bestv[mi][r];
                bestq[mi][r] = gt ? q0 : bestq[mi][r];
            }
        #pragma unroll
        for (int mi = 0; mi < 4; ++mi)
            #pragma unroll
            for (int r = 0; r < 4; ++r) {
                float v = acc[mi][1][r];
                bool gt = v > bestv[mi][r];
                bestv[mi][r] = gt ? v : bestv[mi][r];
                bestq[mi][r] = gt ? (q0 + 16u) : bestq[mi][r];
            }
        q0 += 64u;

        __syncthreads();             // staged buffer landed; all reads of sB[x] done
        x ^= 1;
    }

    // final: pack (acc = s+64 > 0 -> float bits monotone as uint),
    // shuffle-reduce over r15 (stays in q4 group), 1 atomic/row/wave
    #pragma unroll
    for (int mi = 0; mi < 4; ++mi)
        #pragma unroll
        for (int r = 0; r < 4; ++r) {
            u64 pk = ((u64)__float_as_uint(bestv[mi][r]) << 32)
                   | (u64)(0xFFFFFFFFu - bestq[mi][r]);
            #pragma unroll
            for (int d = 1; d < 16; d <<= 1) {
                u64 o = __shfl_xor((unsigned long long)pk, d);
                pk = o > pk ? o : pk;
            }
            if (r15 == 0)
                atomicMax(&packed[p0 + wm * 64 + mi * 16 + q4 * 4 + r], pk);
        }
}

// ---------------------------------------------------------------------------
// L: loss from the argmax's own similarity value (no gather).
// Decode: hi = bits(s+64) -> s = asfloat(hi) - 64; lo = ~q.
__global__ void loss_kernel(const u64* __restrict__ packed,
                            const float* __restrict__ sumsq_a, const float* __restrict__ sumsq_b,
                            float* __restrict__ out) {
    int p = blockIdx.x * 256 + threadIdx.x;
    u64 pk = packed[p];
    float s = __uint_as_float((u32)(pk >> 32)) - 64.0f;
    u32 q = 0xFFFFFFFFu - (u32)(pk & 0xFFFFFFFFull);
    float A = sumsq_a[p], B = sumsq_b[q];
    float dot = s * (sqrtf(B + EPS) + EPS);
    float cossim = dot / ((sqrtf(A) + EPS) * (sqrtf(B) + EPS));
    float v = (1.0f - cossim) * (1.0f / (float)HW);
    #pragma unroll
    for (int d = 1; d < 64; d <<= 1) v += __shfl_xor(v, d);
    if ((threadIdx.x & 63) == 0) atomicAdd(out, v);
}

// ---------------------------------------------------------------------------
extern "C" void kernel_launch(void* const* d_in, const int* in_sizes, int n_in,
                              void* d_out, int out_size, void* d_ws, size_t ws_size,
                              hipStream_t stream) {
    const float* a = (const float*)d_in[0];
    const float* b = (const float*)d_in[1];
    float* out = (float*)d_out;
    char* ws = (char*)d_ws;

    u8*    aF      = (u8*)ws;                                    // 4 MB
    u8*    bF      = (u8*)(ws + (size_t)4 * 1024 * 1024);        // 4 MB
    float* sumsq_a = (float*)(ws + (size_t)8 * 1024 * 1024);     // 64 KB
    float* sumsq_b = sumsq_a + HW;
    u64*   packed  = (u64*)(sumsq_b + HW);                       // 128 KB
    float* apart   = (float*)(ws + (size_t)8 * 1024 * 1024 + 256 * 1024);  // 1 MB
    float* bpart   = apart + 16 * HW;                                       // 1 MB

    prep1_kernel<<<dim3(1024), 256, 0, stream>>>(a, b, apart, bpart, packed, out);
    prep2_kernel<<<dim3(HW / 16), 256, 0, stream>>>(a, b, apart, bpart,
                                                    sumsq_a, sumsq_b, aF, bF);
    gemm_argmax<<<dim3((HW / BM) * (HW / NG)), 256, 0, stream>>>(aF, bF, packed);
    loss_kernel<<<dim3(HW / 256), 256, 0, stream>>>(packed, sumsq_a, sumsq_b, out);
}